// Round 2
// baseline (351.953 us; speedup 1.0000x reference)
//
#include <hip/hip_runtime.h>
#include <hip/hip_bf16.h>

typedef __bf16 bf16x8 __attribute__((ext_vector_type(8)));
typedef float floatx4 __attribute__((ext_vector_type(4)));

// ---- Cl(3) Cayley table, row i = first operand, col j = second. p = i*8+j ----
constexpr int TK[64] = {
  0,1,2,3,4,5,6,7,
  1,0,4,5,2,3,7,6,
  2,4,0,6,1,7,3,5,
  3,5,6,0,7,1,2,4,
  4,2,1,7,0,6,5,3,
  5,3,7,1,6,0,4,2,
  6,7,3,2,5,4,0,1,
  7,6,5,4,3,2,1,0
};
constexpr float SGN[64] = {
  1, 1, 1, 1, 1, 1, 1, 1,
  1, 1, 1, 1, 1, 1, 1, 1,
  1,-1, 1, 1,-1,-1, 1,-1,
  1,-1,-1, 1, 1,-1,-1, 1,
  1,-1, 1, 1,-1,-1, 1,-1,
  1,-1,-1, 1, 1,-1,-1, 1,
  1, 1,-1, 1,-1, 1,-1,-1,
  1, 1,-1, 1,-1, 1,-1,-1
};

__device__ __forceinline__ void async16(const void* g, void* l) {
  __builtin_amdgcn_global_load_lds(
      (const __attribute__((address_space(1))) void*)g,
      (__attribute__((address_space(3))) void*)l, 16, 0, 0);
}

// ---- Kernel A: cast+transpose weights to bf16 B^T layout (n-major, k contiguous) ----
__global__ __launch_bounds__(256) void conv_w(
    const float* __restrict__ Wg, const float* __restrict__ Wu, const float* __restrict__ Wd,
    __bf16* __restrict__ Bg, __bf16* __restrict__ Bu, __bf16* __restrict__ Bd)
{
  int idx = blockIdx.x * 256 + threadIdx.x;   // 0..262143
  {
    int n = idx >> 8, k = idx & 255;          // Bg/Bu: [1024][256]
    Bg[idx] = (__bf16)Wg[k * 1024 + n];
    Bu[idx] = (__bf16)Wu[k * 1024 + n];
  }
  {
    int n = idx >> 10, k = idx & 1023;        // Bd: [256][1024]
    Bd[idx] = (__bf16)Wd[k * 256 + n];
  }
}

// ---- Kernel B: geometric product + gate mix + LayerNorm -> bf16 flat [65536][256] ----
__global__ __launch_bounds__(256) void geo_ln(
    const float* __restrict__ X,   // [8192][8][256]
    const float* __restrict__ IW,  // [64]
    const float* __restrict__ GG,  // [1]
    const float* __restrict__ LW, const float* __restrict__ LB,
    __bf16* __restrict__ F)        // [65536][256]
{
  __shared__ float sw[64];
  __shared__ float smix[8 * 256];
  __shared__ float sstat[16];
  const int t = threadIdx.x;
  const int tok = blockIdx.x;

  if (t < 64) sw[t] = SGN[t] / (1.f + __expf(-IW[t]));

  float xv[8];
  #pragma unroll
  for (int b = 0; b < 8; ++b) xv[b] = X[(size_t)tok * 2048 + b * 256 + t];
  const float g = 1.f / (1.f + __expf(-GG[0]));

  __syncthreads();

  float geo[8] = {0.f, 0.f, 0.f, 0.f, 0.f, 0.f, 0.f, 0.f};
  #pragma unroll
  for (int p = 0; p < 64; ++p)
    geo[TK[p]] += xv[p >> 3] * xv[p & 7] * sw[p];

  float mv[8];
  #pragma unroll
  for (int b = 0; b < 8; ++b) {
    mv[b] = g * geo[b] + (1.f - g) * xv[b];
    smix[b * 256 + t] = mv[b];
  }
  __syncthreads();

  const int wv = t >> 6, lane = t & 63;
  #pragma unroll
  for (int s = 0; s < 2; ++s) {
    int b = wv * 2 + s;
    float v0 = smix[b * 256 + lane];
    float v1 = smix[b * 256 + 64 + lane];
    float v2 = smix[b * 256 + 128 + lane];
    float v3 = smix[b * 256 + 192 + lane];
    float sum = v0 + v1 + v2 + v3;
    float sq  = v0*v0 + v1*v1 + v2*v2 + v3*v3;
    #pragma unroll
    for (int off = 32; off > 0; off >>= 1) {
      sum += __shfl_xor(sum, off, 64);
      sq  += __shfl_xor(sq,  off, 64);
    }
    if (lane == 0) {
      float mu  = sum * (1.f / 256.f);
      float var = sq * (1.f / 256.f) - mu * mu;
      sstat[b]     = mu;
      sstat[8 + b] = rsqrtf(var + 1e-5f);
    }
  }
  __syncthreads();

  const float lw = LW[t], lb = LB[t];
  #pragma unroll
  for (int b = 0; b < 8; ++b) {
    float v = (mv[b] - sstat[b]) * sstat[8 + b] * lw + lb;
    F[(size_t)(tok * 8 + b) * 256 + t] = (__bf16)v;
  }
}

// ---- Kernel C: fused gate+up GEMM + SwiGLU -> h bf16 [65536][1024] ----
// tile 256m x 64f (x2 matrices). BK=64, XOR-swizzled LDS (conflict-free b128 reads).
// LDS layout: row-major [R][64], slot s (8 bf16) of row r stored at slot s^(r&7).
__global__ __launch_bounds__(256, 2) void gemm_gateup(
    const __bf16* __restrict__ A,   // flat [65536][256]
    const __bf16* __restrict__ Bg,  // [1024][256]
    const __bf16* __restrict__ Bu,  // [1024][256]
    __bf16* __restrict__ H)         // [65536][1024]
{
  __shared__ __bf16 sA[256 * 64];   // 32 KB
  __shared__ __bf16 sBg[64 * 64];   // 8 KB
  __shared__ __bf16 sBu[64 * 64];   // 8 KB
  const int t = threadIdx.x;
  const int m0 = blockIdx.x * 256;
  const int f0 = blockIdx.y * 64;
  const int lane = t & 63, wv = t >> 6;
  const int l15 = lane & 15, quad = lane >> 4;

  // staging offsets (element offsets into A / Bg / Bu), fixed per thread
  int aoff[8], boff[2];
  #pragma unroll
  for (int i = 0; i < 8; ++i) {
    int idx = i * 256 + t, row = idx >> 3, slot = idx & 7;
    int gseg = slot ^ (row & 7);
    aoff[i] = (m0 + row) * 256 + gseg * 8;
  }
  #pragma unroll
  for (int i = 0; i < 2; ++i) {
    int idx = i * 256 + t, row = idx >> 3, slot = idx & 7;
    int gseg = slot ^ (row & 7);
    boff[i] = (f0 + row) * 256 + gseg * 8;
  }

  floatx4 zero = {0.f, 0.f, 0.f, 0.f};
  floatx4 accg[4][4], accu[4][4];
  #pragma unroll
  for (int i = 0; i < 4; ++i)
    #pragma unroll
    for (int j = 0; j < 4; ++j) { accg[i][j] = zero; accu[i][j] = zero; }

  const int xr = l15 & 7;                 // row-dependent xor term (row&7 == l15&7)
  for (int k = 0; k < 4; ++k) {           // k0 = k*64
    const int kk = k * 64;
    #pragma unroll
    for (int i = 0; i < 8; ++i) async16(A + aoff[i] + kk, &sA[(i * 256 + t) * 8]);
    #pragma unroll
    for (int i = 0; i < 2; ++i) {
      async16(Bg + boff[i] + kk, &sBg[(i * 256 + t) * 8]);
      async16(Bu + boff[i] + kk, &sBu[(i * 256 + t) * 8]);
    }
    __syncthreads();

    #pragma unroll
    for (int s = 0; s < 2; ++s) {
      const int slot = (s * 4 + quad) ^ xr;
      bf16x8 av[4], bg[4], bu[4];
      #pragma unroll
      for (int i = 0; i < 4; ++i) {
        int r = wv * 64 + i * 16 + l15;
        av[i] = *(const bf16x8*)&sA[r * 64 + slot * 8];
      }
      #pragma unroll
      for (int j = 0; j < 4; ++j) {
        int r = j * 16 + l15;
        bg[j] = *(const bf16x8*)&sBg[r * 64 + slot * 8];
        bu[j] = *(const bf16x8*)&sBu[r * 64 + slot * 8];
      }
      #pragma unroll
      for (int i = 0; i < 4; ++i)
        #pragma unroll
        for (int j = 0; j < 4; ++j) {
          accg[i][j] = __builtin_amdgcn_mfma_f32_16x16x32_bf16(av[i], bg[j], accg[i][j], 0, 0, 0);
          accu[i][j] = __builtin_amdgcn_mfma_f32_16x16x32_bf16(av[i], bu[j], accu[i][j], 0, 0, 0);
        }
    }
    __syncthreads();
  }

  #pragma unroll
  for (int i = 0; i < 4; ++i)
    #pragma unroll
    for (int j = 0; j < 4; ++j)
      #pragma unroll
      for (int r = 0; r < 4; ++r) {
        int m = m0 + wv * 64 + i * 16 + quad * 4 + r;
        int f = f0 + j * 16 + l15;
        float gv = accg[i][j][r];
        float uv = accu[i][j][r];
        float hv = (gv / (1.f + __expf(-gv))) * uv;
        H[(size_t)m * 1024 + f] = (__bf16)hv;
      }
}

// ---- Kernel D: down GEMM + residual. tile 128m x 256n, BK=64, swizzled LDS ----
__global__ __launch_bounds__(256, 2) void gemm_down(
    const __bf16* __restrict__ A,   // h [65536][1024]
    const __bf16* __restrict__ B,   // Wd^T [256][1024]
    const float* __restrict__ X,
    float* __restrict__ O)
{
  __shared__ __bf16 sA[128 * 64];   // 16 KB
  __shared__ __bf16 sB[256 * 64];   // 32 KB
  const int t = threadIdx.x;
  const int m0 = blockIdx.x * 128;
  const int lane = t & 63, wv = t >> 6;
  const int wm = wv & 1, wn = wv >> 1;
  const int l15 = lane & 15, quad = lane >> 4;

  int aoff[4], boff[8];
  #pragma unroll
  for (int i = 0; i < 4; ++i) {
    int idx = i * 256 + t, row = idx >> 3, slot = idx & 7;
    int gseg = slot ^ (row & 7);
    aoff[i] = (m0 + row) * 1024 + gseg * 8;
  }
  #pragma unroll
  for (int i = 0; i < 8; ++i) {
    int idx = i * 256 + t, row = idx >> 3, slot = idx & 7;
    int gseg = slot ^ (row & 7);
    boff[i] = row * 1024 + gseg * 8;
  }

  floatx4 zero = {0.f, 0.f, 0.f, 0.f};
  floatx4 acc[4][8];
  #pragma unroll
  for (int i = 0; i < 4; ++i)
    #pragma unroll
    for (int j = 0; j < 8; ++j) acc[i][j] = zero;

  const int xr = l15 & 7;
  for (int k = 0; k < 16; ++k) {    // k0 = k*64
    const int kk = k * 64;
    #pragma unroll
    for (int i = 0; i < 4; ++i) async16(A + aoff[i] + kk, &sA[(i * 256 + t) * 8]);
    #pragma unroll
    for (int i = 0; i < 8; ++i) async16(B + boff[i] + kk, &sB[(i * 256 + t) * 8]);
    __syncthreads();

    #pragma unroll
    for (int s = 0; s < 2; ++s) {
      const int slot = (s * 4 + quad) ^ xr;
      bf16x8 av[4], bv[8];
      #pragma unroll
      for (int i = 0; i < 4; ++i) {
        int r = wm * 64 + i * 16 + l15;
        av[i] = *(const bf16x8*)&sA[r * 64 + slot * 8];
      }
      #pragma unroll
      for (int j = 0; j < 8; ++j) {
        int r = wn * 128 + j * 16 + l15;
        bv[j] = *(const bf16x8*)&sB[r * 64 + slot * 8];
      }
      #pragma unroll
      for (int i = 0; i < 4; ++i)
        #pragma unroll
        for (int j = 0; j < 8; ++j)
          acc[i][j] = __builtin_amdgcn_mfma_f32_16x16x32_bf16(av[i], bv[j], acc[i][j], 0, 0, 0);
    }
    __syncthreads();
  }

  #pragma unroll
  for (int i = 0; i < 4; ++i)
    #pragma unroll
    for (int j = 0; j < 8; ++j)
      #pragma unroll
      for (int r = 0; r < 4; ++r) {
        int m = m0 + wm * 64 + i * 16 + quad * 4 + r;
        int n = wn * 128 + j * 16 + l15;
        size_t o = (size_t)m * 256 + n;
        O[o] = X[o] + acc[i][j][r];
      }
}

extern "C" void kernel_launch(void* const* d_in, const int* in_sizes, int n_in,
                              void* d_out, int out_size, void* d_ws, size_t ws_size,
                              hipStream_t stream) {
  const float* x   = (const float*)d_in[0];
  const float* iw  = (const float*)d_in[1];
  const float* gg  = (const float*)d_in[2];
  const float* lnw = (const float*)d_in[3];
  const float* lnb = (const float*)d_in[4];
  const float* Wg  = (const float*)d_in[5];
  const float* Wu  = (const float*)d_in[6];
  const float* Wd  = (const float*)d_in[7];
  float* out = (float*)d_out;

  char* ws = (char*)d_ws;
  __bf16* flat = (__bf16*)(ws);                      // 32 MB
  __bf16* h    = (__bf16*)(ws + 33554432);           // 128 MB
  __bf16* Bg   = (__bf16*)(ws + 167772160);          // 512 KB
  __bf16* Bu   = (__bf16*)(ws + 168296448);          // 512 KB
  __bf16* Bd   = (__bf16*)(ws + 168820736);          // 512 KB

  conv_w<<<1024, 256, 0, stream>>>(Wg, Wu, Wd, Bg, Bu, Bd);
  geo_ln<<<8192, 256, 0, stream>>>(x, iw, gg, lnw, lnb, flat);
  gemm_gateup<<<dim3(256, 16), 256, 0, stream>>>(flat, Bg, Bu, h);
  gemm_down<<<512, 256, 0, stream>>>(h, Bd, x, out);
}

// Round 3
// 286.762 us; speedup vs baseline: 1.2273x; 1.2273x over previous
//
#include <hip/hip_runtime.h>
#include <hip/hip_bf16.h>

typedef __bf16 bf16x8 __attribute__((ext_vector_type(8)));
typedef float floatx4 __attribute__((ext_vector_type(4)));

// ---- Cl(3) Cayley table, row i = first operand, col j = second. p = i*8+j ----
constexpr int TK[64] = {
  0,1,2,3,4,5,6,7,
  1,0,4,5,2,3,7,6,
  2,4,0,6,1,7,3,5,
  3,5,6,0,7,1,2,4,
  4,2,1,7,0,6,5,3,
  5,3,7,1,6,0,4,2,
  6,7,3,2,5,4,0,1,
  7,6,5,4,3,2,1,0
};
constexpr float SGN[64] = {
  1, 1, 1, 1, 1, 1, 1, 1,
  1, 1, 1, 1, 1, 1, 1, 1,
  1,-1, 1, 1,-1,-1, 1,-1,
  1,-1,-1, 1, 1,-1,-1, 1,
  1,-1, 1, 1,-1,-1, 1,-1,
  1,-1,-1, 1, 1,-1,-1, 1,
  1, 1,-1, 1,-1, 1,-1,-1,
  1, 1,-1, 1,-1, 1,-1,-1
};

__device__ __forceinline__ void async16(const void* g, void* l) {
  __builtin_amdgcn_global_load_lds(
      (const __attribute__((address_space(1))) void*)g,
      (__attribute__((address_space(3))) void*)l, 16, 0, 0);
}

// ---- Kernel A: LDS-tiled transpose+cast fp32 [K][N] -> bf16 [N][K] ----
__global__ __launch_bounds__(256) void transpose_cast(
    const float* __restrict__ src, __bf16* __restrict__ dst, int K, int N)
{
  __shared__ float s[32 * 33];
  const int t = threadIdx.x;
  const int k0 = blockIdx.y * 32, n0 = blockIdx.x * 32;
  const int r = t >> 5, c = t & 31;
  #pragma unroll
  for (int i = 0; i < 4; ++i)
    s[(r + i * 8) * 33 + c] = src[(size_t)(k0 + r + i * 8) * N + n0 + c];
  __syncthreads();
  #pragma unroll
  for (int i = 0; i < 4; ++i)
    dst[(size_t)(n0 + r + i * 8) * K + k0 + c] = (__bf16)s[c * 33 + r + i * 8];
}

// ---- Kernel B: geometric product + gate mix + LayerNorm -> bf16 flat [65536][256] ----
__global__ __launch_bounds__(256) void geo_ln(
    const float* __restrict__ X,   // [8192][8][256]
    const float* __restrict__ IW,  // [64]
    const float* __restrict__ GG,  // [1]
    const float* __restrict__ LW, const float* __restrict__ LB,
    __bf16* __restrict__ F)        // [65536][256]
{
  __shared__ float sw[64];
  __shared__ float smix[8 * 256];
  __shared__ float sstat[16];
  const int t = threadIdx.x;
  const int tok = blockIdx.x;

  if (t < 64) sw[t] = SGN[t] / (1.f + __expf(-IW[t]));

  float xv[8];
  #pragma unroll
  for (int b = 0; b < 8; ++b) xv[b] = X[(size_t)tok * 2048 + b * 256 + t];
  const float g = 1.f / (1.f + __expf(-GG[0]));

  __syncthreads();

  float geo[8] = {0.f, 0.f, 0.f, 0.f, 0.f, 0.f, 0.f, 0.f};
  #pragma unroll
  for (int p = 0; p < 64; ++p)
    geo[TK[p]] += xv[p >> 3] * xv[p & 7] * sw[p];

  float mv[8];
  #pragma unroll
  for (int b = 0; b < 8; ++b) {
    mv[b] = g * geo[b] + (1.f - g) * xv[b];
    smix[b * 256 + t] = mv[b];
  }
  __syncthreads();

  const int wv = t >> 6, lane = t & 63;
  #pragma unroll
  for (int s = 0; s < 2; ++s) {
    int b = wv * 2 + s;
    float v0 = smix[b * 256 + lane];
    float v1 = smix[b * 256 + 64 + lane];
    float v2 = smix[b * 256 + 128 + lane];
    float v3 = smix[b * 256 + 192 + lane];
    float sum = v0 + v1 + v2 + v3;
    float sq  = v0*v0 + v1*v1 + v2*v2 + v3*v3;
    #pragma unroll
    for (int off = 32; off > 0; off >>= 1) {
      sum += __shfl_xor(sum, off, 64);
      sq  += __shfl_xor(sq,  off, 64);
    }
    if (lane == 0) {
      float mu  = sum * (1.f / 256.f);
      float var = sq * (1.f / 256.f) - mu * mu;
      sstat[b]     = mu;
      sstat[8 + b] = rsqrtf(var + 1e-5f);
    }
  }
  __syncthreads();

  const float lw = LW[t], lb = LB[t];
  #pragma unroll
  for (int b = 0; b < 8; ++b) {
    float v = (mv[b] - sstat[b]) * sstat[8 + b] * lw + lb;
    F[(size_t)(tok * 8 + b) * 256 + t] = (__bf16)v;
  }
}

// ---- Kernel C: fused gate+up GEMM + SwiGLU -> h bf16 [65536][1024] ----
// tile 128m x 64f, BK=64, XOR-swizzled LDS (16B slots, slot^(row&7)) -> conflict-free.
// grid (16 f, 512 m): x-fastest dispatch makes the 16 blocks sharing an A-tile
// temporally adjacent -> A read ~once from HBM.
__global__ __launch_bounds__(256, 3) void gemm_gateup(
    const __bf16* __restrict__ A,   // flat [65536][256]
    const __bf16* __restrict__ Bg,  // [1024][256]
    const __bf16* __restrict__ Bu,  // [1024][256]
    __bf16* __restrict__ H)         // [65536][1024]
{
  __shared__ __bf16 sA[128 * 64];   // 16 KB
  __shared__ __bf16 sBg[64 * 64];   // 8 KB
  __shared__ __bf16 sBu[64 * 64];   // 8 KB
  const int t = threadIdx.x;
  const int f0 = blockIdx.x * 64;
  const int m0 = blockIdx.y * 128;
  const int lane = t & 63, wv = t >> 6;
  const int wm = wv & 1, wf = wv >> 1;
  const int l15 = lane & 15, quad = lane >> 4;

  int aoff[4], boff[2];
  #pragma unroll
  for (int i = 0; i < 4; ++i) {
    int idx = i * 256 + t, row = idx >> 3, slot = idx & 7;
    aoff[i] = (m0 + row) * 256 + (slot ^ (row & 7)) * 8;
  }
  #pragma unroll
  for (int i = 0; i < 2; ++i) {
    int idx = i * 256 + t, row = idx >> 3, slot = idx & 7;
    boff[i] = (f0 + row) * 256 + (slot ^ (row & 7)) * 8;
  }

  floatx4 zero = {0.f, 0.f, 0.f, 0.f};
  floatx4 accg[4][2], accu[4][2];
  #pragma unroll
  for (int i = 0; i < 4; ++i)
    #pragma unroll
    for (int j = 0; j < 2; ++j) { accg[i][j] = zero; accu[i][j] = zero; }

  const int xr = l15 & 7;
  for (int k = 0; k < 4; ++k) {     // k0 = k*64
    const int kk = k * 64;
    #pragma unroll
    for (int i = 0; i < 4; ++i) async16(A + aoff[i] + kk, &sA[(i * 256 + t) * 8]);
    #pragma unroll
    for (int i = 0; i < 2; ++i) {
      async16(Bg + boff[i] + kk, &sBg[(i * 256 + t) * 8]);
      async16(Bu + boff[i] + kk, &sBu[(i * 256 + t) * 8]);
    }
    __syncthreads();

    #pragma unroll
    for (int s = 0; s < 2; ++s) {
      const int slot = (s * 4 + quad) ^ xr;
      bf16x8 av[4], bg[2], bu[2];
      #pragma unroll
      for (int i = 0; i < 4; ++i) {
        int r = wm * 64 + i * 16 + l15;
        av[i] = *(const bf16x8*)&sA[r * 64 + slot * 8];
      }
      #pragma unroll
      for (int j = 0; j < 2; ++j) {
        int r = wf * 32 + j * 16 + l15;
        bg[j] = *(const bf16x8*)&sBg[r * 64 + slot * 8];
        bu[j] = *(const bf16x8*)&sBu[r * 64 + slot * 8];
      }
      #pragma unroll
      for (int i = 0; i < 4; ++i)
        #pragma unroll
        for (int j = 0; j < 2; ++j) {
          accg[i][j] = __builtin_amdgcn_mfma_f32_16x16x32_bf16(av[i], bg[j], accg[i][j], 0, 0, 0);
          accu[i][j] = __builtin_amdgcn_mfma_f32_16x16x32_bf16(av[i], bu[j], accu[i][j], 0, 0, 0);
        }
    }
    __syncthreads();
  }

  #pragma unroll
  for (int i = 0; i < 4; ++i)
    #pragma unroll
    for (int j = 0; j < 2; ++j)
      #pragma unroll
      for (int r = 0; r < 4; ++r) {
        int m = m0 + wm * 64 + i * 16 + quad * 4 + r;
        int f = f0 + wf * 32 + j * 16 + l15;
        float gv = accg[i][j][r];
        float uv = accu[i][j][r];
        float hv = (gv / (1.f + __expf(-gv))) * uv;
        H[(size_t)m * 1024 + f] = (__bf16)hv;
      }
}

// ---- Kernel D: down GEMM + residual. tile 128m x 256n, BK=64, swizzled LDS ----
__global__ __launch_bounds__(256, 2) void gemm_down(
    const __bf16* __restrict__ A,   // h [65536][1024]
    const __bf16* __restrict__ B,   // Wd^T [256][1024]
    const float* __restrict__ X,
    float* __restrict__ O)
{
  __shared__ __bf16 sA[128 * 64];   // 16 KB
  __shared__ __bf16 sB[256 * 64];   // 32 KB
  const int t = threadIdx.x;
  const int m0 = blockIdx.x * 128;
  const int lane = t & 63, wv = t >> 6;
  const int wm = wv & 1, wn = wv >> 1;
  const int l15 = lane & 15, quad = lane >> 4;

  int aoff[4], boff[8];
  #pragma unroll
  for (int i = 0; i < 4; ++i) {
    int idx = i * 256 + t, row = idx >> 3, slot = idx & 7;
    aoff[i] = (m0 + row) * 1024 + (slot ^ (row & 7)) * 8;
  }
  #pragma unroll
  for (int i = 0; i < 8; ++i) {
    int idx = i * 256 + t, row = idx >> 3, slot = idx & 7;
    boff[i] = row * 1024 + (slot ^ (row & 7)) * 8;
  }

  floatx4 zero = {0.f, 0.f, 0.f, 0.f};
  floatx4 acc[4][8];
  #pragma unroll
  for (int i = 0; i < 4; ++i)
    #pragma unroll
    for (int j = 0; j < 8; ++j) acc[i][j] = zero;

  const int xr = l15 & 7;
  for (int k = 0; k < 16; ++k) {    // k0 = k*64
    const int kk = k * 64;
    #pragma unroll
    for (int i = 0; i < 4; ++i) async16(A + aoff[i] + kk, &sA[(i * 256 + t) * 8]);
    #pragma unroll
    for (int i = 0; i < 8; ++i) async16(B + boff[i] + kk, &sB[(i * 256 + t) * 8]);
    __syncthreads();

    #pragma unroll
    for (int s = 0; s < 2; ++s) {
      const int slot = (s * 4 + quad) ^ xr;
      bf16x8 av[4], bv[8];
      #pragma unroll
      for (int i = 0; i < 4; ++i) {
        int r = wm * 64 + i * 16 + l15;
        av[i] = *(const bf16x8*)&sA[r * 64 + slot * 8];
      }
      #pragma unroll
      for (int j = 0; j < 8; ++j) {
        int r = wn * 128 + j * 16 + l15;
        bv[j] = *(const bf16x8*)&sB[r * 64 + slot * 8];
      }
      #pragma unroll
      for (int i = 0; i < 4; ++i)
        #pragma unroll
        for (int j = 0; j < 8; ++j)
          acc[i][j] = __builtin_amdgcn_mfma_f32_16x16x32_bf16(av[i], bv[j], acc[i][j], 0, 0, 0);
    }
    __syncthreads();
  }

  #pragma unroll
  for (int i = 0; i < 4; ++i)
    #pragma unroll
    for (int j = 0; j < 8; ++j)
      #pragma unroll
      for (int r = 0; r < 4; ++r) {
        int m = m0 + wm * 64 + i * 16 + quad * 4 + r;
        int n = wn * 128 + j * 16 + l15;
        size_t o = (size_t)m * 256 + n;
        O[o] = X[o] + acc[i][j][r];
      }
}

extern "C" void kernel_launch(void* const* d_in, const int* in_sizes, int n_in,
                              void* d_out, int out_size, void* d_ws, size_t ws_size,
                              hipStream_t stream) {
  const float* x   = (const float*)d_in[0];
  const float* iw  = (const float*)d_in[1];
  const float* gg  = (const float*)d_in[2];
  const float* lnw = (const float*)d_in[3];
  const float* lnb = (const float*)d_in[4];
  const float* Wg  = (const float*)d_in[5];
  const float* Wu  = (const float*)d_in[6];
  const float* Wd  = (const float*)d_in[7];
  float* out = (float*)d_out;

  char* ws = (char*)d_ws;
  __bf16* flat = (__bf16*)(ws);                      // 32 MB
  __bf16* h    = (__bf16*)(ws + 33554432);           // 128 MB
  __bf16* Bg   = (__bf16*)(ws + 167772160);          // 512 KB
  __bf16* Bu   = (__bf16*)(ws + 168296448);          // 512 KB
  __bf16* Bd   = (__bf16*)(ws + 168820736);          // 512 KB

  transpose_cast<<<dim3(32, 8),  256, 0, stream>>>(Wg, Bg, 256, 1024);
  transpose_cast<<<dim3(32, 8),  256, 0, stream>>>(Wu, Bu, 256, 1024);
  transpose_cast<<<dim3(8, 32),  256, 0, stream>>>(Wd, Bd, 1024, 256);
  geo_ln<<<8192, 256, 0, stream>>>(x, iw, gg, lnw, lnb, flat);
  gemm_gateup<<<dim3(16, 512), 256, 0, stream>>>(flat, Bg, Bu, h);
  gemm_down<<<512, 256, 0, stream>>>(h, Bd, x, out);
}